// Round 1
// baseline (159.539 us; speedup 1.0000x reference)
//
#include <hip/hip_runtime.h>

// PolynomialLayer: in (N,3) f32 -> out (N,10) f32
// out row = [1, x0, x1, x2, x0*x0, x0*x1, x0*x2, x1*x1, x1*x2, x2*x2]
// Memory-bound: 96 MB read + 320 MB write. Process 4 rows/thread so both
// loads (3x float4) and stores (10x float4) are fully 16B-vectorized.

__global__ __launch_bounds__(256) void poly4_kernel(const float4* __restrict__ in4,
                                                    float4* __restrict__ out4,
                                                    int nChunks) {
    int idx = blockIdx.x * blockDim.x + threadIdx.x;
    int stride = gridDim.x * blockDim.x;
    for (int c = idx; c < nChunks; c += stride) {
        // 4 rows = 12 floats = 3 float4
        float4 a = in4[3 * c + 0];  // r0: a.x a.y a.z | r1: a.w ...
        float4 b = in4[3 * c + 1];  // r1: b.x b.y | r2: b.z b.w ...
        float4 d = in4[3 * c + 2];  // r2: d.x | r3: d.y d.z d.w
        float r[4][3] = {{a.x, a.y, a.z},
                         {a.w, b.x, b.y},
                         {b.z, b.w, d.x},
                         {d.y, d.z, d.w}};
        float o[40];
#pragma unroll
        for (int i = 0; i < 4; ++i) {
            float x0 = r[i][0], x1 = r[i][1], x2 = r[i][2];
            o[i * 10 + 0] = 1.0f;
            o[i * 10 + 1] = x0;
            o[i * 10 + 2] = x1;
            o[i * 10 + 3] = x2;
            o[i * 10 + 4] = x0 * x0;
            o[i * 10 + 5] = x0 * x1;
            o[i * 10 + 6] = x0 * x2;
            o[i * 10 + 7] = x1 * x1;
            o[i * 10 + 8] = x1 * x2;
            o[i * 10 + 9] = x2 * x2;
        }
        // 40 floats = 10 float4
        float4* po = &out4[10 * (long long)c];
#pragma unroll
        for (int j = 0; j < 10; ++j) {
            po[j] = make_float4(o[4 * j + 0], o[4 * j + 1], o[4 * j + 2], o[4 * j + 3]);
        }
    }
}

// Tail handler for n % 4 != 0 (not hit at N=8e6, kept for safety)
__global__ void poly_tail_kernel(const float* __restrict__ in,
                                 float* __restrict__ out,
                                 int startRow, int nRows) {
    int i = startRow + blockIdx.x * blockDim.x + threadIdx.x;
    if (i >= nRows) return;
    float x0 = in[3 * (long long)i + 0];
    float x1 = in[3 * (long long)i + 1];
    float x2 = in[3 * (long long)i + 2];
    float* p = &out[10 * (long long)i];
    p[0] = 1.0f; p[1] = x0; p[2] = x1; p[3] = x2;
    p[4] = x0 * x0; p[5] = x0 * x1; p[6] = x0 * x2;
    p[7] = x1 * x1; p[8] = x1 * x2; p[9] = x2 * x2;
}

extern "C" void kernel_launch(void* const* d_in, const int* in_sizes, int n_in,
                              void* d_out, int out_size, void* d_ws, size_t ws_size,
                              hipStream_t stream) {
    const float* in = (const float*)d_in[0];
    float* out = (float*)d_out;
    int nRows = in_sizes[0] / 3;
    int nChunks = nRows / 4;

    if (nChunks > 0) {
        int block = 256;
        int maxBlocks = 2048;  // 256 CUs x 8 blocks, grid-stride the rest
        int blocks = (nChunks + block - 1) / block;
        if (blocks > maxBlocks) blocks = maxBlocks;
        poly4_kernel<<<blocks, block, 0, stream>>>((const float4*)in, (float4*)out, nChunks);
    }
    int done = nChunks * 4;
    int tail = nRows - done;
    if (tail > 0) {
        poly_tail_kernel<<<(tail + 255) / 256, 256, 0, stream>>>(in, out, done, nRows);
    }
}